// Round 11
// baseline (42.114 us; speedup 1.0000x reference)
//
#include <hip/hip_runtime.h>

// ============================================================================
// PGALoss, analytically reduced:
//   per-point loss = sqrt(1 + d^2) + d,  d = NN distance
//   out = 0.5 * sum_dir clip((mean loss - 1)/2, 0, 1)
// d^2 = min_p(||p||^2 - 2 q.p) + ||q||^2
//
// R11: R10's MFMA nn (proven, absmax 0.0) unchanged. The reduce's bursty
// f64 atomicAdd (CAS-loop storm on 2 addresses: ~25us, the hidden floor of
// R2-R10) replaced by a single-block deterministic tree reduce - zero
// atomics on the accumulators.
// ============================================================================

typedef short short8 __attribute__((ext_vector_type(8)));
typedef float f32x16 __attribute__((ext_vector_type(16)));

#define TPB 256
#define PS  8     // point-split: blocks = 4 * (N/256) * PS = 1024

// ws: [64) d2min[QT] u32 | +QT*4 PParr[QT] f32
//     | +QT*8 Abuf[QT*16 ushort] | then Bbuf[QT*16 ushort]

__device__ __forceinline__ unsigned short bf16h(float f) {
    unsigned u = __float_as_uint(f);
    return (unsigned short)((u + 0x7fffu + ((u >> 16) & 1u)) >> 16);
}
__device__ __forceinline__ float bf16v(unsigned short h) {
    return __uint_as_float((unsigned)h << 16);
}

__global__ __launch_bounds__(256)
void prep_kernel(const float* __restrict__ src, const float* __restrict__ tgt,
                 unsigned short* __restrict__ Abuf, unsigned short* __restrict__ Bbuf,
                 float* __restrict__ PParr, unsigned* __restrict__ d2min, int N) {
    const int g = blockIdx.x * 256 + threadIdx.x;    // [0, 4N)
    const int QT = 4 * N;
    if (g >= QT) return;
    d2min[g] = 0x7f7f7f7fu;                          // +3.39e38

    const int twoN = 2 * N;
    const float* in = (g >= twoN) ? tgt : src;
    const int i = (g >= twoN) ? (g - twoN) : g;
    const float x = in[3*i], y = in[3*i+1], z = in[3*i+2];
    const float pp = x*x + y*y + z*z;
    PParr[g] = pp;

    alignas(16) unsigned short A16[16];
    alignas(16) unsigned short B16[16];
    const float q[3] = {x, y, z};
    #pragma unroll
    for (int d = 0; d < 3; ++d) {
        unsigned short qh = bf16h(q[d]);
        unsigned short ql = bf16h(q[d] - bf16v(qh));
        B16[d] = qh; B16[4+d] = ql; B16[8+d] = qh;
        const float t = -2.0f * q[d];
        unsigned short th = bf16h(t);
        unsigned short tl = bf16h(t - bf16v(th));
        A16[d] = th; A16[4+d] = th; A16[8+d] = tl;
    }
    const unsigned short pph = bf16h(pp);
    const unsigned short ppl = bf16h(pp - bf16v(pph));
    A16[3] = pph; A16[7] = ppl; A16[11] = 0;
    B16[3] = 0x3F80u; B16[7] = 0x3F80u; B16[11] = 0;  // bf16 1.0
    #pragma unroll
    for (int s = 12; s < 16; ++s) { A16[s] = 0; B16[s] = 0; }

    // fragment packet: tile = g>>5 (1024B), row r = g&31:
    //   k 0..7 at tile*512 + r*8 (ushort units), k 8..15 at +256
    const size_t tile = (size_t)(g >> 5), r = (size_t)(g & 31);
    unsigned short* Ad = Abuf + tile * 512 + r * 8;
    unsigned short* Bd = Bbuf + tile * 512 + r * 8;
    *(short8*)(Ad)       = *(const short8*)(A16);
    *(short8*)(Ad + 256) = *(const short8*)(A16 + 8);
    *(short8*)(Bd)       = *(const short8*)(B16);
    *(short8*)(Bd + 256) = *(const short8*)(B16 + 8);
}

__global__ __launch_bounds__(TPB)
void nn_kernel(const unsigned short* __restrict__ Abuf,
               const unsigned short* __restrict__ Bbuf,
               const float* __restrict__ PParr,
               unsigned* __restrict__ d2min, int N) {
    const int tid = threadIdx.x;
    const int l = tid & 63;              // lane
    const int w = tid >> 6;              // wave 0..3
    const int nqc  = N >> 8;             // query chunks (256 q per block)
    const int bpt  = nqc * PS;
    const int task = blockIdx.x / bpt;   // 0..3 = s0,s1,t0,t1
    const int rem  = blockIdx.x % bpt;
    const int qc = rem / PS, pc = rem % PS;

    const size_t laneoff = (size_t)((l >> 5) * 256 + (l & 31) * 8);

    const int qbase = task * N + qc * 256 + w * 64;   // 64 queries per wave
    const size_t qt0 = (size_t)(qbase >> 5);
    const short8 b0 = *(const short8*)(Bbuf + qt0 * 512 + laneoff);
    const short8 b1 = *(const short8*)(Bbuf + (qt0 + 1) * 512 + laneoff);

    const int ppb    = N / PS;                        // 1024 points per block
    const int pbase  = (task ^ 2) * N + pc * ppb;
    const int ntiles = ppb >> 5;                      // 32
    const unsigned short* ap = Abuf + (size_t)(pbase >> 5) * 512 + laneoff;

    float best0 = 3.4e38f, best1 = 3.4e38f;
    const f32x16 z = {};
    #pragma unroll 2
    for (int i = 0; i < ntiles; ++i) {
        const short8 a = *(const short8*)ap;          // A-frag: 32 points x K16
        ap += 512;
        f32x16 d0 = __builtin_amdgcn_mfma_f32_32x32x16_bf16(a, b0, z, 0, 0, 0);
        f32x16 d1 = __builtin_amdgcn_mfma_f32_32x32x16_bf16(a, b1, z, 0, 0, 0);
        best0 = fminf(fminf(d0[0],  d0[1]),  best0);  // v_min3_f32 x8
        best0 = fminf(fminf(d0[2],  d0[3]),  best0);
        best0 = fminf(fminf(d0[4],  d0[5]),  best0);
        best0 = fminf(fminf(d0[6],  d0[7]),  best0);
        best0 = fminf(fminf(d0[8],  d0[9]),  best0);
        best0 = fminf(fminf(d0[10], d0[11]), best0);
        best0 = fminf(fminf(d0[12], d0[13]), best0);
        best0 = fminf(fminf(d0[14], d0[15]), best0);
        best1 = fminf(fminf(d1[0],  d1[1]),  best1);
        best1 = fminf(fminf(d1[2],  d1[3]),  best1);
        best1 = fminf(fminf(d1[4],  d1[5]),  best1);
        best1 = fminf(fminf(d1[6],  d1[7]),  best1);
        best1 = fminf(fminf(d1[8],  d1[9]),  best1);
        best1 = fminf(fminf(d1[10], d1[11]), best1);
        best1 = fminf(fminf(d1[12], d1[13]), best1);
        best1 = fminf(fminf(d1[14], d1[15]), best1);
    }
    best0 = fminf(best0, __shfl_xor(best0, 32));
    best1 = fminf(best1, __shfl_xor(best1, 32));
    if (l < 32) {
        const int q0 = qbase + l;
        const float e0 = fmaxf(best0 + PParr[q0], 0.0f);
        const float e1 = fmaxf(best1 + PParr[q0 + 32], 0.0f);
        atomicMin(&d2min[q0],      __float_as_uint(e0));
        atomicMin(&d2min[q0 + 32], __float_as_uint(e1));
    }
}

// single block, 1024 threads, deterministic, zero accumulator atomics
__global__ __launch_bounds__(1024)
void reduce_kernel(const unsigned* __restrict__ d2min,
                   float* __restrict__ out, int N) {
    __shared__ double ws0[16], ws1[16];
    const int t = threadIdx.x;
    const int QT = 4 * N, twoN = 2 * N;
    double s0 = 0.0, s1 = 0.0;
    for (int i = t; i < QT; i += 1024) {             // 32 coalesced iters
        const float d2 = __uint_as_float(d2min[i]);
        const float f = sqrtf(1.0f + d2) + sqrtf(d2);
        if (i < twoN) s0 += (double)f; else s1 += (double)f;
    }
    for (int o = 32; o > 0; o >>= 1) {               // wave tree (fixed order)
        s0 += __shfl_down(s0, o);
        s1 += __shfl_down(s1, o);
    }
    if ((t & 63) == 0) { ws0[t >> 6] = s0; ws1[t >> 6] = s1; }
    __syncthreads();
    if (t == 0) {
        double t0 = 0.0, t1 = 0.0;
        for (int wv = 0; wv < 16; ++wv) { t0 += ws0[wv]; t1 += ws1[wv]; }
        const double inv = 1.0 / (double)twoN;
        double l0 = (t0 * inv - 1.0) * 0.5;
        double l1 = (t1 * inv - 1.0) * 0.5;
        l0 = l0 < 0.0 ? 0.0 : (l0 > 1.0 ? 1.0 : l0);
        l1 = l1 < 0.0 ? 0.0 : (l1 > 1.0 ? 1.0 : l1);
        out[0] = (float)(0.5 * (l0 + l1));
    }
}

extern "C" void kernel_launch(void* const* d_in, const int* in_sizes, int n_in,
                              void* d_out, int out_size, void* d_ws, size_t ws_size,
                              hipStream_t stream) {
    const float* src = (const float*)d_in[0];
    const float* tgt = (const float*)d_in[1];
    float* out = (float*)d_out;

    const int twoN = in_sizes[0] / 3;    // 16384 points per input
    const int N    = twoN / 2;           // 8192
    const int QT   = 4 * N;              // 32768

    unsigned* d2min        = (unsigned*)((char*)d_ws + 64);
    float* PParr           = (float*)((char*)d_ws + 64 + (size_t)QT * 4);
    unsigned short* Abuf   = (unsigned short*)((char*)d_ws + 64 + (size_t)QT * 8);
    unsigned short* Bbuf   = Abuf + (size_t)QT * 16;   // QT*32 bytes each

    prep_kernel<<<(QT + 255) / 256, 256, 0, stream>>>(
        src, tgt, Abuf, Bbuf, PParr, d2min, N);

    const int blocks = 4 * (N >> 8) * PS;   // 1024
    nn_kernel<<<blocks, TPB, 0, stream>>>(Abuf, Bbuf, PParr, d2min, N);

    reduce_kernel<<<1, 1024, 0, stream>>>(d2min, out, N);
}